// Round 1
// baseline (480.744 us; speedup 1.0000x reference)
//
#include <hip/hip_runtime.h>
#include <hip/hip_bf16.h>

#define N_NODES 100000
#define N_RADIAL 16
#define N_CONICAL 16

// ---------------------------------------------------------------------------
// Phase 1: symmetric edge scatter.
// 16 threads per edge-direction; lane ch handles channel ch.
// rows = concat(i, j), cols = concat(j, i)  =>
//   for dir in [0, 2E):  row = idx[dir],  col = (dir < E) ? idx[dir+E] : idx[dir-E]
// sum[row][ch] += x[col][16+ch];  deg[row] += 1 (ch==0 lane only).
// ---------------------------------------------------------------------------
__global__ __launch_bounds__(256) void scatter_kernel(
    const float* __restrict__ x, const int* __restrict__ idx,
    float* __restrict__ sum, float* __restrict__ deg, int E) {
    int tid = blockIdx.x * blockDim.x + threadIdx.x;
    int dir = tid >> 4;
    int ch  = tid & 15;
    if (dir >= 2 * E) return;
    int row = idx[dir];
    int col = (dir < E) ? idx[dir + E] : idx[dir - E];
    float v = x[col * 32 + N_RADIAL + ch];
    atomicAdd(&sum[row * N_CONICAL + ch], v);
    if (ch == 0) atomicAdd(&deg[row], 1.0f);
}

// ---------------------------------------------------------------------------
// Phase 2: per-node MLP.  combined = [x[:, :16], sum/deg] (32) -> 128 -> 32.
// One thread per node; comb[32] + acc[32] live in VGPRs.  W1/W2/b1/b2 are
// accessed with wave-uniform indices -> scalar loads (free alongside VALU).
// ---------------------------------------------------------------------------
__global__ __launch_bounds__(256) void mlp_kernel(
    const float* __restrict__ x, const float* __restrict__ sum,
    const float* __restrict__ deg,
    const float* __restrict__ W1, const float* __restrict__ b1,
    const float* __restrict__ W2, const float* __restrict__ b2,
    float* __restrict__ out, int N) {
    int n = blockIdx.x * blockDim.x + threadIdx.x;
    if (n >= N) return;

    float comb[32];
    #pragma unroll
    for (int c = 0; c < N_RADIAL; c++) comb[c] = x[n * 32 + c];

    float d = deg[n];
    d = (d < 1.0f) ? 1.0f : d;
    float inv = 1.0f / d;
    #pragma unroll
    for (int c = 0; c < N_CONICAL; c++)
        comb[N_RADIAL + c] = sum[n * N_CONICAL + c] * inv;

    float acc[32];
    #pragma unroll
    for (int o = 0; o < 32; o++) acc[o] = b2[o];

    #pragma unroll 4
    for (int k = 0; k < 128; k++) {
        float h = b1[k];
        #pragma unroll
        for (int c = 0; c < 32; c++) h = fmaf(comb[c], W1[c * 128 + k], h);
        h = fmaxf(h, 0.0f);
        #pragma unroll
        for (int o = 0; o < 32; o++) acc[o] = fmaf(h, W2[k * 32 + o], acc[o]);
    }

    #pragma unroll
    for (int o = 0; o < 32; o++) out[n * 32 + o] = acc[o];
}

extern "C" void kernel_launch(void* const* d_in, const int* in_sizes, int n_in,
                              void* d_out, int out_size, void* d_ws, size_t ws_size,
                              hipStream_t stream) {
    const float* x   = (const float*)d_in[0];
    const int*   idx = (const int*)d_in[1];
    const float* W1  = (const float*)d_in[2];
    const float* b1  = (const float*)d_in[3];
    const float* W2  = (const float*)d_in[4];
    const float* b2  = (const float*)d_in[5];
    float* out = (float*)d_out;

    const int E = in_sizes[1] / 2;  // 1,600,000

    // Workspace layout: sum[N_NODES*16] | deg[N_NODES]
    float* sum = (float*)d_ws;
    float* deg = sum + (size_t)N_NODES * N_CONICAL;
    size_t zero_bytes = ((size_t)N_NODES * N_CONICAL + N_NODES) * sizeof(float);
    hipMemsetAsync(d_ws, 0, zero_bytes, stream);

    // Scatter: 2*E directions x 16 channels
    long long total = (long long)2 * E * 16;
    int sblocks = (int)((total + 255) / 256);
    scatter_kernel<<<sblocks, 256, 0, stream>>>(x, idx, sum, deg, E);

    // MLP: one thread per node
    int mblocks = (N_NODES + 255) / 256;
    mlp_kernel<<<mblocks, 256, 0, stream>>>(x, sum, deg, W1, b1, W2, b2, out, N_NODES);
}

// Round 2
// 478.004 us; speedup vs baseline: 1.0057x; 1.0057x over previous
//
#include <hip/hip_runtime.h>
#include <hip/hip_bf16.h>
#include <hip/hip_fp16.h>

#define N_NODES 100000
#define N_RADIAL 16
#define N_CONICAL 16

// ---------------------------------------------------------------------------
// Phase 1: symmetric edge scatter with packed f16 atomics.
// 8 threads per edge-direction; lane c handles channel pair (2c, 2c+1).
//   dir in [0,2E): row = idx[dir], col = (dir < E) ? idx[dir+E] : idx[dir-E]
// sum_h2[row*8 + c] += (half2)x[col][16+2c .. 16+2c+1]   (global_atomic_pk_add_f16)
// deg[row] += 1 (c==0 lane).
// Atomic count: 2E*8 + 2E = 28.8M (was 54.4M scalar f32).
// ---------------------------------------------------------------------------
__global__ __launch_bounds__(256) void scatter_kernel(
    const float* __restrict__ x, const int* __restrict__ idx,
    __half2* __restrict__ sum, float* __restrict__ deg, int E) {
    int tid = blockIdx.x * blockDim.x + threadIdx.x;
    int dir = tid >> 3;
    int c   = tid & 7;
    if (dir >= 2 * E) return;
    int row = idx[dir];
    int col = (dir < E) ? idx[dir + E] : idx[dir - E];
    // coalesced: 8 lanes read the 64B conical block of node `col`
    const float2* xp = (const float2*)(x + (size_t)col * 32 + N_RADIAL);
    float2 v = xp[c];
    __half2 hv = __floats2half2_rn(v.x, v.y);
    unsafeAtomicAdd(&sum[(size_t)row * 8 + c], hv);
    if (c == 0) atomicAdd(&deg[row], 1.0f);
}

// ---------------------------------------------------------------------------
// Phase 2: per-node MLP.  combined = [x[:, :16], sum/deg] (32) -> 128 -> 32.
// One thread per node; comb[32] + acc[32] in VGPRs.
// __launch_bounds__(256, 2): VGPR cap 256 -> no scratch spill (round-1 kernel
// was capped at 44 VGPRs and spilled both arrays -> 150+ us).
// Weights accessed wave-uniformly -> scalar loads on the free SALU pipe.
// ---------------------------------------------------------------------------
__global__ __launch_bounds__(256, 2) void mlp_kernel(
    const float* __restrict__ x, const __half2* __restrict__ sum,
    const float* __restrict__ deg,
    const float* __restrict__ W1, const float* __restrict__ b1,
    const float* __restrict__ W2, const float* __restrict__ b2,
    float* __restrict__ out, int N) {
    int n = blockIdx.x * blockDim.x + threadIdx.x;
    if (n >= N) return;

    float comb[32];
    const float4* xr = (const float4*)(x + (size_t)n * 32);
    #pragma unroll
    for (int c = 0; c < 4; c++) {
        float4 v = xr[c];
        comb[c * 4 + 0] = v.x; comb[c * 4 + 1] = v.y;
        comb[c * 4 + 2] = v.z; comb[c * 4 + 3] = v.w;
    }

    float d = deg[n];
    d = (d < 1.0f) ? 1.0f : d;
    float inv = 1.0f / d;
    const __half2* s2 = sum + (size_t)n * 8;
    #pragma unroll
    for (int c = 0; c < 8; c++) {
        float2 f = __half22float2(s2[c]);
        comb[N_RADIAL + 2 * c]     = f.x * inv;
        comb[N_RADIAL + 2 * c + 1] = f.y * inv;
    }

    float acc[32];
    #pragma unroll
    for (int o = 0; o < 32; o++) acc[o] = b2[o];

    #pragma unroll 4
    for (int k = 0; k < 128; k++) {
        float h = b1[k];
        #pragma unroll
        for (int c = 0; c < 32; c++) h = fmaf(comb[c], W1[c * 128 + k], h);
        h = fmaxf(h, 0.0f);
        #pragma unroll
        for (int o = 0; o < 32; o++) acc[o] = fmaf(h, W2[k * 32 + o], acc[o]);
    }

    float4* op = (float4*)(out + (size_t)n * 32);
    #pragma unroll
    for (int o = 0; o < 8; o++)
        op[o] = make_float4(acc[4 * o], acc[4 * o + 1], acc[4 * o + 2], acc[4 * o + 3]);
}

extern "C" void kernel_launch(void* const* d_in, const int* in_sizes, int n_in,
                              void* d_out, int out_size, void* d_ws, size_t ws_size,
                              hipStream_t stream) {
    const float* x   = (const float*)d_in[0];
    const int*   idx = (const int*)d_in[1];
    const float* W1  = (const float*)d_in[2];
    const float* b1  = (const float*)d_in[3];
    const float* W2  = (const float*)d_in[4];
    const float* b2  = (const float*)d_in[5];
    float* out = (float*)d_out;

    const int E = in_sizes[1] / 2;  // 1,600,000

    // Workspace layout: sum (f16, N_NODES*16 = 3.2 MB) | deg (f32, 0.4 MB)
    __half2* sum = (__half2*)d_ws;
    float*   deg = (float*)((char*)d_ws + (size_t)N_NODES * N_CONICAL * sizeof(__half));
    size_t zero_bytes = (size_t)N_NODES * N_CONICAL * sizeof(__half)
                      + (size_t)N_NODES * sizeof(float);
    hipMemsetAsync(d_ws, 0, zero_bytes, stream);

    // Scatter: 2*E directions x 8 half2-channels
    long long total = (long long)2 * E * 8;
    int sblocks = (int)((total + 255) / 256);
    scatter_kernel<<<sblocks, 256, 0, stream>>>(x, idx, sum, deg, E);

    // MLP: one thread per node
    int mblocks = (N_NODES + 255) / 256;
    mlp_kernel<<<mblocks, 256, 0, stream>>>(x, sum, deg, W1, b1, W2, b2, out, N_NODES);
}